// Round 1
// baseline (113.492 us; speedup 1.0000x reference)
//
#include <hip/hip_runtime.h>
#include <math.h>

#define A_ 64
#define T_ 32
#define B_ 64
#define V_ 12
#define D_ 512
#define TAUF 100.0f

// K1: inverse L2 norms of all text (2048) and video (768) rows -> ws
__global__ void norm_kernel(const float* __restrict__ text,
                            const float* __restrict__ video,
                            float* __restrict__ inv)
{
    int r = blockIdx.x;
    const float* src = (r < A_ * T_) ? (text + (size_t)r * D_)
                                     : (video + (size_t)(r - A_ * T_) * D_);
    int tid = threadIdx.x; // 128 threads, one float4 each (512 floats)
    float4 x = ((const float4*)src)[tid];
    float ss = x.x * x.x + x.y * x.y + x.z * x.z + x.w * x.w;
    for (int m = 32; m >= 1; m >>= 1) ss += __shfl_xor(ss, m);
    __shared__ float red[2];
    if ((tid & 63) == 0) red[tid >> 6] = ss;
    __syncthreads();
    if (tid == 0) {
        float s = red[0] + red[1];
        inv[r] = 1.0f / fmaxf(sqrtf(s), 1e-6f);
    }
}

// K2: one block per (a,b). 384 threads, one per (t,v).
__global__ __launch_bounds__(384)
void fused_kernel(const float* __restrict__ text,
                  const float* __restrict__ video,
                  const int* __restrict__ mask,
                  const float* __restrict__ inv,
                  float* __restrict__ out)
{
    const int a = blockIdx.y;
    const int b = blockIdx.x;
    const int tid = threadIdx.x;      // 0..383
    const int t = tid / V_;           // 0..31
    const int v = tid - t * V_;       // 0..11

    __shared__ float vsh[V_][D_ + 4];     // +4 floats pad -> ~2-way LDS conflicts (free)
    __shared__ float Lsh[T_][V_];         // raw logits
    __shared__ float t2v_sh[T_], v2t_sh[V_];
    __shared__ float w2_sh[T_], wv_sh[V_];
    __shared__ float stats[2];
    __shared__ int   msh[T_];
    __shared__ float red[6];

    // ---- stage video rows (scaled by inv norm) into LDS ----
    const float* vbase = video + (size_t)b * V_ * D_;
    const float* invv = inv + A_ * T_ + b * V_;
    #pragma unroll
    for (int k = 0; k < 4; ++k) {
        int idx = k * 384 + tid;      // 0..1535 float4 slots (12 rows x 128)
        int row = idx >> 7;
        int col = idx & 127;
        float4 x = ((const float4*)(vbase + row * D_))[col];
        float s = invv[row];
        x.x *= s; x.y *= s; x.z *= s; x.w *= s;
        *((float4*)&vsh[row][col * 4]) = x;
    }
    if (tid < T_) msh[tid] = mask[a * T_ + tid];
    __syncthreads();

    // ---- raw logit: dot(text_row, scaled_video_row) * inv_t ----
    const float4* tp = (const float4*)(text + ((size_t)a * T_ + t) * D_);
    const float4* vp = (const float4*)&vsh[v][0];
    float4 acc = {0.f, 0.f, 0.f, 0.f};
    #pragma unroll 8
    for (int k = 0; k < 128; ++k) {
        float4 x = tp[k];
        float4 y = vp[k];
        acc.x += x.x * y.x; acc.y += x.y * y.y;
        acc.z += x.z * y.z; acc.w += x.w * y.w;
    }
    float L = ((acc.x + acc.y) + (acc.z + acc.w)) * inv[a * T_ + t];
    Lsh[t][v] = L;
    __syncthreads();

    // ---- Phase B: row softmax (vps1 -> t2v) on lanes 0..31 of wave0;
    //      column masked softmax (tps1 -> v2t) on lanes 0..11 of wave1 ----
    if (tid < T_) {
        int tmv = msh[tid];
        float l[V_];
        #pragma unroll
        for (int j = 0; j < V_; ++j) l[j] = Lsh[tid][j];
        float t2v;
        if (tmv) {
            float m = -1e30f;
            #pragma unroll
            for (int j = 0; j < V_; ++j) m = fmaxf(m, l[j]);
            float s = 0.f, num = 0.f;
            #pragma unroll
            for (int j = 0; j < V_; ++j) {
                float e = expf(TAUF * (l[j] - m));
                s += e; num += e * l[j];
            }
            t2v = num / s;
        } else {
            // softmax of all-zero logits = uniform -> mean of raw logits
            float s = 0.f;
            #pragma unroll
            for (int j = 0; j < V_; ++j) s += l[j];
            t2v = s * (1.0f / V_);
        }
        t2v_sh[tid] = t2v;
    } else if (tid >= 64 && tid < 64 + V_) {
        int vv = tid - 64;
        float m = -1e30f;
        for (int j = 0; j < T_; ++j) {
            float Lm = msh[j] ? Lsh[j][vv] : 0.0f;
            if (Lm != 0.0f) m = fmaxf(m, Lm);
        }
        float s = 0.f, num = 0.f;
        for (int j = 0; j < T_; ++j) {
            float Lraw = Lsh[j][vv];
            float Lm = msh[j] ? Lraw : 0.0f;
            if (Lm != 0.0f) {
                float e = expf(TAUF * (Lm - m));
                s += e; num += e * Lraw;
            }
        }
        v2t_sh[vv] = num / s;
    }
    __syncthreads();

    // ---- Phase C: tps2 weights (exclude t2v==0) and vps2 weights ----
    if (tid < T_) {
        float val = t2v_sh[tid];
        bool ex = (val == 0.0f);
        float x = ex ? -1e30f : val;
        for (int m = 16; m >= 1; m >>= 1) x = fmaxf(x, __shfl_xor(x, m));
        float w = ex ? 0.0f : expf(TAUF * (val - x));
        float s = w;
        for (int m = 16; m >= 1; m >>= 1) s += __shfl_xor(s, m);
        w2_sh[tid] = w;
        if (tid == 0) stats[0] = s;
    } else if (tid >= 64 && tid < 64 + V_) {
        int vv = tid - 64;
        float m = -1e30f;
        for (int j = 0; j < V_; ++j) m = fmaxf(m, v2t_sh[j]);
        float s = 0.f;
        for (int j = 0; j < V_; ++j) s += expf(TAUF * (v2t_sh[j] - m));
        wv_sh[vv] = expf(TAUF * (v2t_sh[vv] - m));
        if (vv == 0) stats[1] = s;
    }
    __syncthreads();

    // ---- Phase D: out = sum_{t,v} w2[t]*wv[v]*L[t,v] / (W2*Wv) ----
    float part = w2_sh[t] * wv_sh[v] * Lsh[t][v];
    for (int m = 32; m >= 1; m >>= 1) part += __shfl_xor(part, m);
    if ((tid & 63) == 0) red[tid >> 6] = part;
    __syncthreads();
    if (tid == 0) {
        float s = (red[0] + red[1]) + (red[2] + red[3]) + (red[4] + red[5]);
        out[a * B_ + b] = s / (stats[0] * stats[1]);
    }
}

extern "C" void kernel_launch(void* const* d_in, const int* in_sizes, int n_in,
                              void* d_out, int out_size, void* d_ws, size_t ws_size,
                              hipStream_t stream) {
    const float* text  = (const float*)d_in[0];
    const float* video = (const float*)d_in[1];
    const int*   mask  = (const int*)d_in[2];
    float* out = (float*)d_out;
    float* inv = (float*)d_ws;   // 2816 floats

    norm_kernel<<<A_ * T_ + B_ * V_, 128, 0, stream>>>(text, video, inv);
    fused_kernel<<<dim3(B_, A_), 384, 0, stream>>>(text, video, mask, inv, out);
}